// Round 2
// baseline (1993.729 us; speedup 1.0000x reference)
//
#include <hip/hip_runtime.h>
#include <cstdint>
#include <cstddef>

#define NPTS 4096
#define CDIM 64
#define BDIM 8
#define KNN  20
#define ODIM 64
#define RB   128          // rows per block (fused knn)
#define CT   128          // cols per tile
#define NT   (NPTS / CT)  // 32 tiles

// order-preserving float->u32 flip (ascending float == ascending u32)
__device__ __forceinline__ unsigned flip_f32(float d) {
  unsigned bits = __float_as_uint(d);
  return bits ^ (unsigned)(((int)bits >> 31) | 0x80000000u);
}
__device__ __forceinline__ float unflip_f32(unsigned f) {
  unsigned mask = (f >> 31) ? 0x80000000u : 0xFFFFFFFFu;
  return __uint_as_float(f ^ mask);
}

// ---------------------------------------------------------------------------
// sq[b][n] = sum_c x[b][c][n]^2
// ---------------------------------------------------------------------------
__global__ __launch_bounds__(256) void sq_kernel(const float* __restrict__ x,
                                                 float* __restrict__ sq) {
  int g = blockIdx.x * 256 + threadIdx.x;            // g = b*N + n
  int b = g >> 12, n = g & (NPTS - 1);
  const float* xb = x + (size_t)b * CDIM * NPTS + n;
  float s = 0.f;
  #pragma unroll
  for (int c = 0; c < CDIM; ++c) { float v = xb[(size_t)c * NPTS]; s += v * v; }
  sq[g] = s;
}

// ---------------------------------------------------------------------------
// Fused pairwise-dist + top-20 select. One block per 128 rows per batch
// (grid 32x8 = 256 blocks = 1/CU). Per column tile of 128:
//   - 8x8 register-tile fp32 GEMM (ascending-c accumulation, identical
//     numerics to the reference formula sq_r + sq_m - 2*inner)
//   - dist tile -> LDS (stride 132 words)
//   - 128 owner threads scan their row (rotated order, bank-conflict-free)
//     with early-out vs running 20th; sorted (flip(d)<<32|col) list in LDS
//     gives jax.lax.top_k's lexicographic tie-break exactly.
// Bs tile t+1 is prefetched to registers during GEMM t, written after the
// barrier (overlaps the owner scan).
// ---------------------------------------------------------------------------
__global__ __launch_bounds__(256) void knn_fused(const float* __restrict__ x,
                                                 const float* __restrict__ sq,
                                                 int* __restrict__ knn) {
  __shared__ float As[CDIM][RB];                 // 32 KB, lives whole kernel
  __shared__ float Bs[CDIM][CT];                 // 32 KB, rotated per tile
  __shared__ float dt[RB][CT + 4];               // 66 KB dist tile
  __shared__ unsigned long long top[RB][KNN];    // 20 KB sorted top lists

  const int tid = threadIdx.x;
  const int b   = blockIdx.y;
  const int r0  = blockIdx.x * RB;
  const float* xb  = x  + (size_t)b * CDIM * NPTS;
  const float* sqb = sq + (size_t)b * NPTS;

  for (int i = tid; i < RB * KNN; i += 256)
    ((unsigned long long*)top)[i] = ~0ull;

  {  // stage A panel (rows r0..r0+127, all 64 c) and Bs tile 0
    const int col = (tid & 31) * 4;
    const int cr  = tid >> 5;
    #pragma unroll
    for (int p = 0; p < 8; ++p) {
      int c = p * 8 + cr;
      *(float4*)&As[c][col] = *(const float4*)(xb + (size_t)c * NPTS + r0 + col);
      *(float4*)&Bs[c][col] = *(const float4*)(xb + (size_t)c * NPTS + col);
    }
  }
  __syncthreads();

  const int tx = tid & 15, ty = tid >> 4;        // rows ty*8+i ; cols {4tx, 64+4tx}+j
  float sqr[8];
  #pragma unroll
  for (int i = 0; i < 8; ++i) sqr[i] = sqb[r0 + ty * 8 + i];

  // owner-thread running state (valid for tid < RB)
  unsigned long long t19 = ~0ull;
  float d19 = INFINITY;

  for (int t = 0; t < NT; ++t) {
    // prefetch Bs tile t+1 into registers (consumed after barrier1)
    float4 pf[8];
    if (t + 1 < NT) {
      const int col = (tid & 31) * 4;
      const int cr  = tid >> 5;
      const int mt1 = (t + 1) * CT;
      #pragma unroll
      for (int p = 0; p < 8; ++p) {
        int c = p * 8 + cr;
        pf[p] = *(const float4*)(xb + (size_t)c * NPTS + mt1 + col);
      }
    }

    const int mt = t * CT;
    float sqm[8];
    #pragma unroll
    for (int j = 0; j < 4; ++j) {
      sqm[j]     = sqb[mt + tx * 4 + j];
      sqm[4 + j] = sqb[mt + 64 + tx * 4 + j];
    }

    float acc[8][8];
    #pragma unroll
    for (int i = 0; i < 8; ++i)
      #pragma unroll
      for (int j = 0; j < 8; ++j) acc[i][j] = 0.f;

    #pragma unroll 4
    for (int c = 0; c < CDIM; ++c) {
      float a8[8], b8[8];
      *(float4*)&a8[0] = *(const float4*)&As[c][ty * 8];
      *(float4*)&a8[4] = *(const float4*)&As[c][ty * 8 + 4];
      *(float4*)&b8[0] = *(const float4*)&Bs[c][tx * 4];
      *(float4*)&b8[4] = *(const float4*)&Bs[c][64 + tx * 4];
      #pragma unroll
      for (int i = 0; i < 8; ++i)
        #pragma unroll
        for (int j = 0; j < 8; ++j) acc[i][j] += a8[i] * b8[j];
    }

    #pragma unroll
    for (int i = 0; i < 8; ++i) {
      int r = ty * 8 + i;
      float o0[4], o1[4];
      #pragma unroll
      for (int j = 0; j < 4; ++j) {
        o0[j] = sqr[i] + sqm[j]     - 2.0f * acc[i][j];
        o1[j] = sqr[i] + sqm[4 + j] - 2.0f * acc[i][4 + j];
      }
      *(float4*)&dt[r][tx * 4]      = *(float4*)&o0[0];
      *(float4*)&dt[r][64 + tx * 4] = *(float4*)&o1[0];
    }
    __syncthreads();   // dt complete; Bs free to overwrite

    if (tid < RB) {    // owner scan (waves 0-1) — overlaps Bs write below
      const int r = tid;
      const float* drow = &dt[r][0];
      for (int s = 0; s < CT; ++s) {
        int j = (r + s) & (CT - 1);
        float d = drow[j];
        if (!(d > d19)) {               // early-out; robust to sentinel
          unsigned long long cand =
              ((unsigned long long)flip_f32(d) << 32) | (unsigned)(mt + j);
          if (cand < t19) {
            int k = KNN - 1;
            while (k > 0 && top[r][k - 1] > cand) { top[r][k] = top[r][k - 1]; --k; }
            top[r][k] = cand;
            t19 = top[r][KNN - 1];
            unsigned hk = (unsigned)(t19 >> 32);
            d19 = (hk == 0xFFFFFFFFu) ? INFINITY : unflip_f32(hk);
          }
        }
      }
    }
    if (t + 1 < NT) {  // write prefetched tile
      const int col = (tid & 31) * 4;
      const int cr  = tid >> 5;
      #pragma unroll
      for (int p = 0; p < 8; ++p) {
        int c = p * 8 + cr;
        *(float4*)&Bs[c][col] = pf[p];
      }
    }
    __syncthreads();   // Bs ready, scan done
  }

  if (tid < RB) {
    const int r = tid;
    #pragma unroll
    for (int k = 0; k < KNN; ++k)
      knn[((size_t)b * NPTS + r0 + r) * KNN + k] = (int)(unsigned)(top[r][k] & 0xFFFFFFFFu);
  }
}

// ---------------------------------------------------------------------------
// a[b][n][o]  = sum_c (W[o][c]-W[o][c+64]) * x[b][c][n]
// cc[b][n][o] = sum_c  W[o][c+64]          * x[b][c][n]
// Coalesced: lanes = consecutive n; W broadcast from LDS as float4.
// Thread = (o-fragment of 16) x (2 n's). Block covers 128 n, grid 256.
// ---------------------------------------------------------------------------
__global__ __launch_bounds__(256) void proj_kernel(const float* __restrict__ x,
                                                   const float* __restrict__ w,
                                                   float* __restrict__ a,
                                                   float* __restrict__ cc) {
  __shared__ float wa[CDIM][ODIM];
  __shared__ float wc[CDIM][ODIM];
  const int tid = threadIdx.x;
  #pragma unroll
  for (int p = 0; p < 16; ++p) {
    int idx = p * 256 + tid;                       // 0..4095
    int o = idx & 63, c = idx >> 6;
    float w1 = w[o * 128 + c], w2 = w[o * 128 + 64 + c];
    wa[c][o] = w1 - w2;
    wc[c][o] = w2;
  }
  __syncthreads();

  const int og = tid >> 6;                         // o-fragment og*16..+15
  const int nl = tid & 63;
  const int g0 = blockIdx.x * 128;                 // g = b*N + n
  const int b  = g0 >> 12;
  const int n0 = g0 & (NPTS - 1);
  const float* xB = x + (size_t)b * CDIM * NPTS;

  float aa0[16], ac0[16], aa1[16], ac1[16];
  #pragma unroll
  for (int q = 0; q < 16; ++q) { aa0[q] = ac0[q] = aa1[q] = ac1[q] = 0.f; }

  #pragma unroll 4
  for (int c = 0; c < CDIM; ++c) {
    float xv0 = xB[(size_t)c * NPTS + n0 + nl];        // coalesced
    float xv1 = xB[(size_t)c * NPTS + n0 + 64 + nl];
    #pragma unroll
    for (int q4 = 0; q4 < 4; ++q4) {
      float4 va = *(const float4*)&wa[c][og * 16 + q4 * 4];  // broadcast
      float4 vc = *(const float4*)&wc[c][og * 16 + q4 * 4];
      aa0[q4*4+0] += va.x * xv0; aa0[q4*4+1] += va.y * xv0;
      aa0[q4*4+2] += va.z * xv0; aa0[q4*4+3] += va.w * xv0;
      ac0[q4*4+0] += vc.x * xv0; ac0[q4*4+1] += vc.y * xv0;
      ac0[q4*4+2] += vc.z * xv0; ac0[q4*4+3] += vc.w * xv0;
      aa1[q4*4+0] += va.x * xv1; aa1[q4*4+1] += va.y * xv1;
      aa1[q4*4+2] += va.z * xv1; aa1[q4*4+3] += va.w * xv1;
      ac1[q4*4+0] += vc.x * xv1; ac1[q4*4+1] += vc.y * xv1;
      ac1[q4*4+2] += vc.z * xv1; ac1[q4*4+3] += vc.w * xv1;
    }
  }
  size_t ga0 = (size_t)(g0 + nl) * ODIM + og * 16;
  size_t ga1 = (size_t)(g0 + 64 + nl) * ODIM + og * 16;
  #pragma unroll
  for (int q4 = 0; q4 < 4; ++q4) {
    *(float4*)&a [ga0 + q4 * 4] = *(float4*)&aa0[q4 * 4];
    *(float4*)&cc[ga0 + q4 * 4] = *(float4*)&ac0[q4 * 4];
    *(float4*)&a [ga1 + q4 * 4] = *(float4*)&aa1[q4 * 4];
    *(float4*)&cc[ga1 + q4 * 4] = *(float4*)&ac1[q4 * 4];
  }
}

// ---------------------------------------------------------------------------
// out[b][o][n] = relu(inv[o] * max_k(a[b][n][o] + cc[b][knn[n][k]][o]) + bias[o])
// ---------------------------------------------------------------------------
__global__ __launch_bounds__(256) void out_kernel(const float* __restrict__ a,
                                                  const float* __restrict__ cc,
                                                  const int* __restrict__ knn,
                                                  const float* __restrict__ gamma,
                                                  const float* __restrict__ beta,
                                                  const float* __restrict__ mean,
                                                  const float* __restrict__ var,
                                                  float* __restrict__ out) {
  __shared__ float tile[64][65];
  const int tid = threadIdx.x, lane = tid & 63, wv = tid >> 6;
  const int b = blockIdx.y;
  const int n0 = blockIdx.x * 64;
  float inv  = gamma[lane] / sqrtf(var[lane] + 1e-5f);
  float bias = beta[lane] - mean[lane] * inv;
  for (int t = 0; t < 16; ++t) {
    int nl = wv * 16 + t;
    size_t base = (size_t)b * NPTS + (n0 + nl);
    float av = a[base * ODIM + lane];
    const int* kr = knn + base * KNN;
    float m = -INFINITY;
    #pragma unroll
    for (int k = 0; k < KNN; ++k) {
      int j = kr[k];                               // wave-uniform
      float cv = cc[((size_t)b * NPTS + j) * ODIM + lane];
      m = fmaxf(m, av + cv);
    }
    float v = m * inv + bias;
    tile[nl][lane] = v > 0.f ? v : 0.f;
  }
  __syncthreads();
  for (int t = 0; t < 16; ++t) {
    int o = wv * 16 + t;
    out[((size_t)b * ODIM + o) * NPTS + n0 + lane] = tile[lane][o];
  }
}

// ---------------------------------------------------------------------------
extern "C" void kernel_launch(void* const* d_in, const int* in_sizes, int n_in,
                              void* d_out, int out_size, void* d_ws, size_t ws_size,
                              hipStream_t stream) {
  const float* x     = (const float*)d_in[0];
  const float* w     = (const float*)d_in[1];
  const float* gamma = (const float*)d_in[2];
  const float* beta  = (const float*)d_in[3];
  const float* mean  = (const float*)d_in[4];
  const float* var   = (const float*)d_in[5];
  float* out = (float*)d_out;

  char* wsb = (char*)d_ws;
  size_t off = 0;
  int*   knn = (int*)(wsb + off);   off += (size_t)BDIM * NPTS * KNN * 4;   // 2.62 MB
  float* sq  = (float*)(wsb + off); off += (size_t)BDIM * NPTS * 4;         // 0.13 MB
  float* a   = (float*)(wsb + off); off += (size_t)BDIM * NPTS * ODIM * 4;  // 8 MB
  float* cc  = (float*)(wsb + off); off += (size_t)BDIM * NPTS * ODIM * 4;  // 8 MB
  (void)ws_size;

  sq_kernel  <<<BDIM * NPTS / 256, 256, 0, stream>>>(x, sq);
  proj_kernel<<<BDIM * NPTS / 128, 256, 0, stream>>>(x, w, a, cc);
  knn_fused  <<<dim3(NPTS / RB, BDIM), 256, 0, stream>>>(x, sq, knn);
  out_kernel <<<dim3(NPTS / 64, BDIM), 256, 0, stream>>>(a, cc, knn, gamma, beta,
                                                         mean, var, out);
}

// Round 3
// 499.120 us; speedup vs baseline: 3.9945x; 3.9945x over previous
//
#include <hip/hip_runtime.h>
#include <cstdint>
#include <cstddef>

#define NPTS 4096
#define CDIM 64
#define BDIM 8
#define KNN  20
#define ODIM 64

typedef unsigned long long u64;
#define SENT (~0ull)

// order-preserving float->u32 flip (ascending float == ascending u32)
__device__ __forceinline__ unsigned flip_f32(float d) {
  unsigned bits = __float_as_uint(d);
  return bits ^ (unsigned)(((int)bits >> 31) | 0x80000000u);
}

// wave64 all-reduce min (rocPRIM DPP sequence), result uniform via readlane 63
__device__ __forceinline__ unsigned wave_min_u32(unsigned v) {
  unsigned t;
  t = (unsigned)__builtin_amdgcn_update_dpp((int)v, (int)v, 0x111, 0xF, 0xF, false); v = t < v ? t : v;
  t = (unsigned)__builtin_amdgcn_update_dpp((int)v, (int)v, 0x112, 0xF, 0xF, false); v = t < v ? t : v;
  t = (unsigned)__builtin_amdgcn_update_dpp((int)v, (int)v, 0x114, 0xF, 0xF, false); v = t < v ? t : v;
  t = (unsigned)__builtin_amdgcn_update_dpp((int)v, (int)v, 0x118, 0xF, 0xF, false); v = t < v ? t : v;
  t = (unsigned)__builtin_amdgcn_update_dpp((int)v, (int)v, 0x142, 0xA, 0xF, false); v = t < v ? t : v;
  t = (unsigned)__builtin_amdgcn_update_dpp((int)v, (int)v, 0x143, 0xC, 0xF, false); v = t < v ? t : v;
  return (unsigned)__builtin_amdgcn_readlane((int)v, 63);
}

// branchless insert into ascending sorted-3 (u64 lexicographic keys)
__device__ __forceinline__ void ins3(u64& l0, u64& l1, u64& l2, u64 v) {
  u64 a = v < l0 ? v : l0;
  u64 b = v < l0 ? l0 : v;
  u64 c = b < l1 ? b : l1;
  u64 d = b < l1 ? l1 : b;
  u64 e = d < l2 ? d : l2;
  l0 = a; l1 = c; l2 = e;
}

// ---------------------------------------------------------------------------
// sq[b][n] = sum_c x[b][c][n]^2
// ---------------------------------------------------------------------------
__global__ __launch_bounds__(256) void sq_kernel(const float* __restrict__ x,
                                                 float* __restrict__ sq) {
  int g = blockIdx.x * 256 + threadIdx.x;
  int b = g >> 12, n = g & (NPTS - 1);
  const float* xb = x + (size_t)b * CDIM * NPTS + n;
  float s = 0.f;
  #pragma unroll
  for (int c = 0; c < CDIM; ++c) { float v = xb[(size_t)c * NPTS]; s += v * v; }
  sq[g] = s;
}

// ---------------------------------------------------------------------------
// dist rows [g0+by*128, +128) (global row g = b*N + r) vs all m.
// Split-K staging: LDS = 2 x 16KB -> 3 blocks/CU (was 64KB -> 2).
// c ascends across phases => bit-identical accumulation vs round 1.
// ---------------------------------------------------------------------------
__global__ __launch_bounds__(256) void dist_gemm(const float* __restrict__ x,
                                                 const float* __restrict__ sq,
                                                 float* __restrict__ dist,
                                                 int g0) {
  __shared__ float As[32][128];
  __shared__ float Bs[32][128];
  const int tid = threadIdx.x;
  const int mt  = blockIdx.x * 128;
  const int gy  = g0 + blockIdx.y * 128;           // global row base
  const int b   = gy >> 12;
  const int rb  = gy & (NPTS - 1);                 // row base within batch
  const float* xb  = x  + (size_t)b * CDIM * NPTS;
  const float* sqb = sq + (size_t)b * NPTS;

  const int tx = tid & 15, ty = tid >> 4;
  float acc[8][8];
  #pragma unroll
  for (int i = 0; i < 8; ++i)
    #pragma unroll
    for (int j = 0; j < 8; ++j) acc[i][j] = 0.f;

  const int col = (tid & 31) * 4;
  const int crw = tid >> 5;                        // 0..7

  #pragma unroll
  for (int phase = 0; phase < 2; ++phase) {
    #pragma unroll
    for (int p = 0; p < 4; ++p) {
      int cl = p * 8 + crw;                        // 0..31
      int c  = phase * 32 + cl;
      *(float4*)&As[cl][col] = *(const float4*)(xb + (size_t)c * NPTS + rb + col);
      *(float4*)&Bs[cl][col] = *(const float4*)(xb + (size_t)c * NPTS + mt + col);
    }
    __syncthreads();
    #pragma unroll 4
    for (int cl = 0; cl < 32; ++cl) {
      float a8[8], b8[8];
      *(float4*)&a8[0] = *(const float4*)&As[cl][ty * 8];
      *(float4*)&a8[4] = *(const float4*)&As[cl][ty * 8 + 4];
      *(float4*)&b8[0] = *(const float4*)&Bs[cl][tx * 4];
      *(float4*)&b8[4] = *(const float4*)&Bs[cl][64 + tx * 4];
      #pragma unroll
      for (int i = 0; i < 8; ++i)
        #pragma unroll
        for (int j = 0; j < 8; ++j) acc[i][j] += a8[i] * b8[j];
    }
    __syncthreads();
  }

  #pragma unroll
  for (int i = 0; i < 8; ++i) {
    int r = ty * 8 + i;
    float sr = sqb[rb + r];
    float o0[4], o1[4];
    #pragma unroll
    for (int j = 0; j < 4; ++j) {
      o0[j] = sr + sqb[mt + tx * 4 + j]      - 2.0f * acc[i][j];
      o1[j] = sr + sqb[mt + 64 + tx * 4 + j] - 2.0f * acc[i][4 + j];
    }
    float* dr = dist + (size_t)(blockIdx.y * 128 + r) * NPTS + mt;
    *(float4*)(dr + tx * 4)      = *(float4*)&o0[0];
    *(float4*)(dr + 64 + tx * 4) = *(float4*)&o1[0];
  }
}

// ---------------------------------------------------------------------------
// Top-20 smallest (dist, m) per row. One wave per row, streaming:
// lane streams 64 values (16 x float4, m = i*256 + lane*4 + j), keeps a
// branchless sorted-3 of u64 (flip(d)<<12 | m). 20 rounds: DPP wave-min on
// u32 key + DPP min-m tie-break (exact lexicographic = jax.lax.top_k).
// Rare exact fallback: lane that pops all 3 reloads & rebuilds with filter.
// ---------------------------------------------------------------------------
__global__ __launch_bounds__(256) void topk_kernel(const float* __restrict__ dist,
                                                   int* __restrict__ knn,
                                                   int g0) {
  const int lane = threadIdx.x & 63;
  const int wv   = threadIdx.x >> 6;
  const int gl   = blockIdx.x * 4 + wv;            // chunk-local row
  const int g    = g0 + gl;                        // global row (b*N + n)
  const float4* drow4 = (const float4*)(dist + (size_t)gl * NPTS);

  u64 l0 = SENT, l1 = SENT, l2 = SENT;
  #pragma unroll 4
  for (int i = 0; i < 16; ++i) {
    float4 q = drow4[i * 64 + lane];
    unsigned mb = i * 256 + lane * 4;
    ins3(l0, l1, l2, ((u64)flip_f32(q.x) << 12) | mb);
    ins3(l0, l1, l2, ((u64)flip_f32(q.y) << 12) | (mb + 1));
    ins3(l0, l1, l2, ((u64)flip_f32(q.z) << 12) | (mb + 2));
    ins3(l0, l1, l2, ((u64)flip_f32(q.w) << 12) | (mb + 3));
  }

  u64 last = 0;
  bool done = false;
  int myidx = 0;
  for (int r = 0; r < KNN; ++r) {
    bool need = (l0 == SENT) && !done;
    if (__any(need)) {
      if (need) {                                  // rare exact rebuild
        l0 = l1 = l2 = SENT;
        for (int i = 0; i < 16; ++i) {
          float4 q = drow4[i * 64 + lane];
          unsigned mb = i * 256 + lane * 4;
          u64 v;
          v = ((u64)flip_f32(q.x) << 12) | mb;       ins3(l0, l1, l2, v > last ? v : SENT);
          v = ((u64)flip_f32(q.y) << 12) | (mb + 1); ins3(l0, l1, l2, v > last ? v : SENT);
          v = ((u64)flip_f32(q.z) << 12) | (mb + 2); ins3(l0, l1, l2, v > last ? v : SENT);
          v = ((u64)flip_f32(q.w) << 12) | (mb + 3); ins3(l0, l1, l2, v > last ? v : SENT);
        }
        if (l0 == SENT) done = true;
      }
    }
    unsigned keyH = (unsigned)(l0 >> 12);
    unsigned wkey = wave_min_u32(keyH);
    unsigned mc   = (keyH == wkey) ? (unsigned)(l0 & 0xFFF) : 0xFFFFFFFFu;
    unsigned wm   = wave_min_u32(mc);
    myidx = (lane == r) ? (int)wm : myidx;
    u64 wsel = ((u64)wkey << 12) | wm;
    bool win = (l0 == wsel);
    l0 = win ? l1 : l0;
    l1 = win ? l2 : l1;
    l2 = win ? SENT : l2;
    last = wsel;
  }
  if (lane < KNN) knn[(size_t)g * KNN + lane] = myidx;
}

// ---------------------------------------------------------------------------
// a[b][n][o]  = sum_c (W[o][c]-W[o][c+64]) * x[b][c][n]
// cc[b][n][o] = sum_c  W[o][c+64]          * x[b][c][n]
// ---------------------------------------------------------------------------
__global__ __launch_bounds__(256) void proj_kernel(const float* __restrict__ x,
                                                   const float* __restrict__ w,
                                                   float* __restrict__ a,
                                                   float* __restrict__ cc) {
  __shared__ float wa[CDIM][ODIM];
  __shared__ float wc[CDIM][ODIM];
  const int tid = threadIdx.x;
  #pragma unroll
  for (int p = 0; p < 16; ++p) {
    int idx = p * 256 + tid;
    int o = idx & 63, c = idx >> 6;
    float w1 = w[o * 128 + c], w2 = w[o * 128 + 64 + c];
    wa[c][o] = w1 - w2;
    wc[c][o] = w2;
  }
  __syncthreads();

  const int og = tid >> 6;
  const int nl = tid & 63;
  const int g0 = blockIdx.x * 128;
  const int b  = g0 >> 12;
  const int n0 = g0 & (NPTS - 1);
  const float* xB = x + (size_t)b * CDIM * NPTS;

  float aa0[16], ac0[16], aa1[16], ac1[16];
  #pragma unroll
  for (int q = 0; q < 16; ++q) { aa0[q] = ac0[q] = aa1[q] = ac1[q] = 0.f; }

  #pragma unroll 4
  for (int c = 0; c < CDIM; ++c) {
    float xv0 = xB[(size_t)c * NPTS + n0 + nl];
    float xv1 = xB[(size_t)c * NPTS + n0 + 64 + nl];
    #pragma unroll
    for (int q4 = 0; q4 < 4; ++q4) {
      float4 va = *(const float4*)&wa[c][og * 16 + q4 * 4];
      float4 vc = *(const float4*)&wc[c][og * 16 + q4 * 4];
      aa0[q4*4+0] += va.x * xv0; aa0[q4*4+1] += va.y * xv0;
      aa0[q4*4+2] += va.z * xv0; aa0[q4*4+3] += va.w * xv0;
      ac0[q4*4+0] += vc.x * xv0; ac0[q4*4+1] += vc.y * xv0;
      ac0[q4*4+2] += vc.z * xv0; ac0[q4*4+3] += vc.w * xv0;
      aa1[q4*4+0] += va.x * xv1; aa1[q4*4+1] += va.y * xv1;
      aa1[q4*4+2] += va.z * xv1; aa1[q4*4+3] += va.w * xv1;
      ac1[q4*4+0] += vc.x * xv1; ac1[q4*4+1] += vc.y * xv1;
      ac1[q4*4+2] += vc.z * xv1; ac1[q4*4+3] += vc.w * xv1;
    }
  }
  size_t ga0 = (size_t)(g0 + nl) * ODIM + og * 16;
  size_t ga1 = (size_t)(g0 + 64 + nl) * ODIM + og * 16;
  #pragma unroll
  for (int q4 = 0; q4 < 4; ++q4) {
    *(float4*)&a [ga0 + q4 * 4] = *(float4*)&aa0[q4 * 4];
    *(float4*)&cc[ga0 + q4 * 4] = *(float4*)&ac0[q4 * 4];
    *(float4*)&a [ga1 + q4 * 4] = *(float4*)&aa1[q4 * 4];
    *(float4*)&cc[ga1 + q4 * 4] = *(float4*)&ac1[q4 * 4];
  }
}

// ---------------------------------------------------------------------------
// out[b][o][n] = relu(inv[o] * max_k(a[b][n][o] + cc[b][knn[n][k]][o]) + bias[o])
// ---------------------------------------------------------------------------
__global__ __launch_bounds__(256) void out_kernel(const float* __restrict__ a,
                                                  const float* __restrict__ cc,
                                                  const int* __restrict__ knn,
                                                  const float* __restrict__ gamma,
                                                  const float* __restrict__ beta,
                                                  const float* __restrict__ mean,
                                                  const float* __restrict__ var,
                                                  float* __restrict__ out) {
  __shared__ float tile[64][65];
  const int tid = threadIdx.x, lane = tid & 63, wv = tid >> 6;
  const int b = blockIdx.y;
  const int n0 = blockIdx.x * 64;
  float inv  = gamma[lane] / sqrtf(var[lane] + 1e-5f);
  float bias = beta[lane] - mean[lane] * inv;
  for (int t = 0; t < 16; ++t) {
    int nl = wv * 16 + t;
    size_t base = (size_t)b * NPTS + (n0 + nl);
    float av = a[base * ODIM + lane];
    const int* kr = knn + base * KNN;
    float m = -INFINITY;
    #pragma unroll
    for (int k = 0; k < KNN; ++k) {
      int j = kr[k];
      float cv = cc[((size_t)b * NPTS + j) * ODIM + lane];
      m = fmaxf(m, av + cv);
    }
    float v = m * inv + bias;
    tile[nl][lane] = v > 0.f ? v : 0.f;
  }
  __syncthreads();
  for (int t = 0; t < 16; ++t) {
    int o = wv * 16 + t;
    out[((size_t)b * ODIM + o) * NPTS + n0 + lane] = tile[lane][o];
  }
}

// ---------------------------------------------------------------------------
extern "C" void kernel_launch(void* const* d_in, const int* in_sizes, int n_in,
                              void* d_out, int out_size, void* d_ws, size_t ws_size,
                              hipStream_t stream) {
  const float* x     = (const float*)d_in[0];
  const float* w     = (const float*)d_in[1];
  const float* gamma = (const float*)d_in[2];
  const float* beta  = (const float*)d_in[3];
  const float* mean  = (const float*)d_in[4];
  const float* var   = (const float*)d_in[5];
  float* out = (float*)d_out;

  char* wsb = (char*)d_ws;
  size_t off = 0;
  int*   knn = (int*)(wsb + off);   off += (size_t)BDIM * NPTS * KNN * 4;   // 2.62 MB
  float* sq  = (float*)(wsb + off); off += (size_t)BDIM * NPTS * 4;         // 0.13 MB
  float* a   = (float*)(wsb + off); off += (size_t)BDIM * NPTS * ODIM * 4;  // 8 MB
  float* cc  = (float*)(wsb + off); off += (size_t)BDIM * NPTS * ODIM * 4;  // 8 MB
  float* dist = (float*)(wsb + off);

  // largest chunk (rows across all batches) fitting ws; cap 8192 rows
  // (128 MB) so topk reads stay L3-resident
  int chunk = 128;
  for (int c2 = 8192; c2 >= 128; c2 >>= 1) {
    if (off + (size_t)c2 * NPTS * 4 <= ws_size) { chunk = c2; break; }
  }

  sq_kernel  <<<BDIM * NPTS / 256, 256, 0, stream>>>(x, sq);
  proj_kernel<<<BDIM * NPTS / 128, 256, 0, stream>>>(x, w, a, cc);

  const int total_rows = BDIM * NPTS;
  for (int g0 = 0; g0 < total_rows; g0 += chunk) {
    dist_gemm  <<<dim3(NPTS / 128, chunk / 128), 256, 0, stream>>>(x, sq, dist, g0);
    topk_kernel<<<chunk / 4, 256, 0, stream>>>(dist, knn, g0);
  }

  out_kernel<<<dim3(NPTS / 64, BDIM), 256, 0, stream>>>(a, cc, knn, gamma, beta,
                                                        mean, var, out);
}

// Round 4
// 387.908 us; speedup vs baseline: 5.1397x; 1.2867x over previous
//
#include <hip/hip_runtime.h>
#include <cstdint>
#include <cstddef>

#define NPTS 4096
#define CDIM 64
#define BDIM 8
#define KNN  20
#define ODIM 64

typedef unsigned long long u64;
typedef _Float16 f16;
using f16x8 = __attribute__((ext_vector_type(8))) _Float16;
using f32x4 = __attribute__((ext_vector_type(4))) float;
#define SENT (~0ull)

// order-preserving float->u32 flip (ascending float == ascending u32)
__device__ __forceinline__ unsigned flip_f32(float d) {
  unsigned bits = __float_as_uint(d);
  return bits ^ (unsigned)(((int)bits >> 31) | 0x80000000u);
}

// wave64 all-reduce min (DPP), result uniform via readlane 63
__device__ __forceinline__ unsigned wave_min_u32(unsigned v) {
  unsigned t;
  t = (unsigned)__builtin_amdgcn_update_dpp((int)v, (int)v, 0x111, 0xF, 0xF, false); v = t < v ? t : v;
  t = (unsigned)__builtin_amdgcn_update_dpp((int)v, (int)v, 0x112, 0xF, 0xF, false); v = t < v ? t : v;
  t = (unsigned)__builtin_amdgcn_update_dpp((int)v, (int)v, 0x114, 0xF, 0xF, false); v = t < v ? t : v;
  t = (unsigned)__builtin_amdgcn_update_dpp((int)v, (int)v, 0x118, 0xF, 0xF, false); v = t < v ? t : v;
  t = (unsigned)__builtin_amdgcn_update_dpp((int)v, (int)v, 0x142, 0xA, 0xF, false); v = t < v ? t : v;
  t = (unsigned)__builtin_amdgcn_update_dpp((int)v, (int)v, 0x143, 0xC, 0xF, false); v = t < v ? t : v;
  return (unsigned)__builtin_amdgcn_readlane((int)v, 63);
}

// branchless insert into ascending sorted-4 (u64 lexicographic keys)
__device__ __forceinline__ void ins4(u64& l0, u64& l1, u64& l2, u64& l3, u64 v) {
  u64 a = v < l0 ? v : l0;
  u64 b = v < l0 ? l0 : v;
  u64 c = b < l1 ? b : l1;
  u64 d = b < l1 ? l1 : b;
  u64 e = d < l2 ? d : l2;
  u64 f = d < l2 ? l2 : d;
  u64 g = f < l3 ? f : l3;
  l0 = a; l1 = c; l2 = e; l3 = g;
}

// ---------------------------------------------------------------------------
// sq[b][n] = sum_c x[b][c][n]^2
// ---------------------------------------------------------------------------
__global__ __launch_bounds__(256) void sq_kernel(const float* __restrict__ x,
                                                 float* __restrict__ sq) {
  int g = blockIdx.x * 256 + threadIdx.x;
  int b = g >> 12, n = g & (NPTS - 1);
  const float* xb = x + (size_t)b * CDIM * NPTS + n;
  float s = 0.f;
  #pragma unroll
  for (int c = 0; c < CDIM; ++c) { float v = xb[(size_t)c * NPTS]; s += v * v; }
  sq[g] = s;
}

// ---------------------------------------------------------------------------
// MFMA fp16x3 dist: dist[r][m] = sq_r + sq_m - 2 * (hi_r.hi_m + hi_r.lo_m +
// lo_r.hi_m), error ~1e-6 (below fp32 reorder noise). 128x128 tile/block,
// 4 waves of 64x64, 96 x mfma_f32_16x16x32_f16 per wave. LDS: hi/lo panels
// [128][64] f16, XOR-swizzled for uniform-bank ds_read_b128 frag reads.
// ---------------------------------------------------------------------------
__device__ __forceinline__ int swz(int r) { return (r & 7) ^ ((r >> 3) & 7); }

__device__ __forceinline__ f16x8 ldfrag(const f16* base, int row, int k0) {
  int byte = (row * 128 + k0 * 2) ^ (swz(row) << 4);
  return *(const f16x8*)((const char*)base + byte);
}
__device__ __forceinline__ void stfrag(f16* base, int n, int c, f16 v) {
  int byte = (n * 128 + c * 2) ^ (swz(n) << 4);
  *(f16*)((char*)base + byte) = v;
}

__global__ __launch_bounds__(256) void dist_gemm(const float* __restrict__ x,
                                                 const float* __restrict__ sq,
                                                 float* __restrict__ dist,
                                                 int g0) {
  __shared__ f16 XAhi[128 * 64], XAlo[128 * 64];
  __shared__ f16 XBhi[128 * 64], XBlo[128 * 64];
  __shared__ float sqR[128], sqM[128];

  const int tid = threadIdx.x;
  const int mt  = blockIdx.x * 128;
  const int gy  = g0 + blockIdx.y * 128;
  const int b   = gy >> 12;
  const int rb  = gy & (NPTS - 1);
  const float* xb  = x  + (size_t)b * CDIM * NPTS;
  const float* sqb = sq + (size_t)b * NPTS;

  if (tid < 128)       sqR[tid]       = sqb[rb + tid];
  else                 sqM[tid - 128] = sqb[mt + tid - 128];

  // stage hi/lo fp16 panels (rows rb.., cols mt..), swizzled
  const int nq = tid & 31;           // n-quad
  const int cp = tid >> 5;           // 0..7
  #pragma unroll
  for (int p = 0; p < 8; ++p) {
    int c = p * 8 + cp;
    float4 va = *(const float4*)(xb + (size_t)c * NPTS + rb + nq * 4);
    float4 vb = *(const float4*)(xb + (size_t)c * NPTS + mt + nq * 4);
    #pragma unroll
    for (int i = 0; i < 4; ++i) {
      float v = (&va.x)[i];
      f16 h = (f16)v; f16 l = (f16)(v - (float)h);
      stfrag(XAhi, nq * 4 + i, c, h);
      stfrag(XAlo, nq * 4 + i, c, l);
      float w = (&vb.x)[i];
      f16 hw = (f16)w; f16 lw = (f16)(w - (float)hw);
      stfrag(XBhi, nq * 4 + i, c, hw);
      stfrag(XBlo, nq * 4 + i, c, lw);
    }
  }
  __syncthreads();

  const int lane = tid & 63, wid = tid >> 6;
  const int wy = wid >> 1, wx = wid & 1;       // 2x2 waves, 64x64 each
  const int lrow = lane & 15;
  const int lk   = (lane >> 4) * 8;

  f32x4 acc[4][4];
  #pragma unroll
  for (int i = 0; i < 4; ++i)
    #pragma unroll
    for (int j = 0; j < 4; ++j) acc[i][j] = (f32x4){0.f, 0.f, 0.f, 0.f};

  #pragma unroll
  for (int ks = 0; ks < 2; ++ks) {
    const int kb = ks * 32 + lk;
    f16x8 Ah[4], Al[4], Bh[4], Bl[4];
    #pragma unroll
    for (int rs = 0; rs < 4; ++rs) {
      int r = wy * 64 + rs * 16 + lrow;
      Ah[rs] = ldfrag(XAhi, r, kb);
      Al[rs] = ldfrag(XAlo, r, kb);
    }
    #pragma unroll
    for (int ms = 0; ms < 4; ++ms) {
      int m = wx * 64 + ms * 16 + lrow;
      Bh[ms] = ldfrag(XBhi, m, kb);
      Bl[ms] = ldfrag(XBlo, m, kb);
    }
    #pragma unroll
    for (int rs = 0; rs < 4; ++rs)
      #pragma unroll
      for (int ms = 0; ms < 4; ++ms) {
        acc[rs][ms] = __builtin_amdgcn_mfma_f32_16x16x32_f16(Ah[rs], Bh[ms], acc[rs][ms], 0, 0, 0);
        acc[rs][ms] = __builtin_amdgcn_mfma_f32_16x16x32_f16(Ah[rs], Bl[ms], acc[rs][ms], 0, 0, 0);
        acc[rs][ms] = __builtin_amdgcn_mfma_f32_16x16x32_f16(Al[rs], Bh[ms], acc[rs][ms], 0, 0, 0);
      }
  }

  // epilogue: C layout col=lane&15 (m), row=(lane>>4)*4+reg (r)
  #pragma unroll
  for (int rs = 0; rs < 4; ++rs)
    #pragma unroll
    for (int ms = 0; ms < 4; ++ms) {
      int mg = mt + wx * 64 + ms * 16 + lrow;
      float sm = sqM[wx * 64 + ms * 16 + lrow];
      #pragma unroll
      for (int reg = 0; reg < 4; ++reg) {
        int rl = wy * 64 + rs * 16 + (lane >> 4) * 4 + reg;
        float v = sqR[rl] + sm - 2.0f * acc[rs][ms][reg];
        dist[(size_t)(blockIdx.y * 128 + rl) * NPTS + mg] = v;
      }
    }
}

// ---------------------------------------------------------------------------
// Top-20 smallest (dist, m) per row. One wave per row, streaming sorted-4
// of u64 (flip(d)<<12 | m) per lane + 20 rounds of DPP wave-min with exact
// min-m tie-break. Rare exact rebuild when a lane pops all 4.
// ---------------------------------------------------------------------------
__global__ __launch_bounds__(256) void topk_kernel(const float* __restrict__ dist,
                                                   int* __restrict__ knn,
                                                   int g0) {
  const int lane = threadIdx.x & 63;
  const int wv   = threadIdx.x >> 6;
  const int gl   = blockIdx.x * 4 + wv;
  const int g    = g0 + gl;
  const float4* drow4 = (const float4*)(dist + (size_t)gl * NPTS);

  u64 l0 = SENT, l1 = SENT, l2 = SENT, l3 = SENT;
  #pragma unroll 4
  for (int i = 0; i < 16; ++i) {
    float4 q = drow4[i * 64 + lane];
    unsigned mb = i * 256 + lane * 4;
    ins4(l0, l1, l2, l3, ((u64)flip_f32(q.x) << 12) | mb);
    ins4(l0, l1, l2, l3, ((u64)flip_f32(q.y) << 12) | (mb + 1));
    ins4(l0, l1, l2, l3, ((u64)flip_f32(q.z) << 12) | (mb + 2));
    ins4(l0, l1, l2, l3, ((u64)flip_f32(q.w) << 12) | (mb + 3));
  }

  u64 last = 0;
  bool done = false;
  int myidx = 0;
  for (int r = 0; r < KNN; ++r) {
    bool need = (l0 == SENT) && !done;
    if (__any(need)) {
      if (need) {                                  // rare exact rebuild
        l0 = l1 = l2 = l3 = SENT;
        for (int i = 0; i < 16; ++i) {
          float4 q = drow4[i * 64 + lane];
          unsigned mb = i * 256 + lane * 4;
          u64 v;
          v = ((u64)flip_f32(q.x) << 12) | mb;       ins4(l0, l1, l2, l3, v > last ? v : SENT);
          v = ((u64)flip_f32(q.y) << 12) | (mb + 1); ins4(l0, l1, l2, l3, v > last ? v : SENT);
          v = ((u64)flip_f32(q.z) << 12) | (mb + 2); ins4(l0, l1, l2, l3, v > last ? v : SENT);
          v = ((u64)flip_f32(q.w) << 12) | (mb + 3); ins4(l0, l1, l2, l3, v > last ? v : SENT);
        }
        if (l0 == SENT) done = true;
      }
    }
    unsigned keyH = (unsigned)(l0 >> 12);
    unsigned wkey = wave_min_u32(keyH);
    unsigned mc   = (keyH == wkey) ? (unsigned)(l0 & 0xFFF) : 0xFFFFFFFFu;
    unsigned wm   = wave_min_u32(mc);
    myidx = (lane == r) ? (int)wm : myidx;
    u64 wsel = ((u64)wkey << 12) | wm;
    bool win = (l0 == wsel);
    l0 = win ? l1 : l0;
    l1 = win ? l2 : l1;
    l2 = win ? l3 : l2;
    l3 = win ? SENT : l3;
    last = wsel;
  }
  if (lane < KNN) knn[(size_t)g * KNN + lane] = myidx;
}

// ---------------------------------------------------------------------------
// a[b][n][o]  = sum_c (W[o][c]-W[o][c+64]) * x[b][c][n]
// cc[b][n][o] = sum_c  W[o][c+64]          * x[b][c][n]
// ---------------------------------------------------------------------------
__global__ __launch_bounds__(256) void proj_kernel(const float* __restrict__ x,
                                                   const float* __restrict__ w,
                                                   float* __restrict__ a,
                                                   float* __restrict__ cc) {
  __shared__ float wa[CDIM][ODIM];
  __shared__ float wc[CDIM][ODIM];
  const int tid = threadIdx.x;
  #pragma unroll
  for (int p = 0; p < 16; ++p) {
    int idx = p * 256 + tid;
    int o = idx & 63, c = idx >> 6;
    float w1 = w[o * 128 + c], w2 = w[o * 128 + 64 + c];
    wa[c][o] = w1 - w2;
    wc[c][o] = w2;
  }
  __syncthreads();

  const int og = tid >> 6;
  const int nl = tid & 63;
  const int g0 = blockIdx.x * 128;
  const int b  = g0 >> 12;
  const int n0 = g0 & (NPTS - 1);
  const float* xB = x + (size_t)b * CDIM * NPTS;

  float aa0[16], ac0[16], aa1[16], ac1[16];
  #pragma unroll
  for (int q = 0; q < 16; ++q) { aa0[q] = ac0[q] = aa1[q] = ac1[q] = 0.f; }

  #pragma unroll 4
  for (int c = 0; c < CDIM; ++c) {
    float xv0 = xB[(size_t)c * NPTS + n0 + nl];
    float xv1 = xB[(size_t)c * NPTS + n0 + 64 + nl];
    #pragma unroll
    for (int q4 = 0; q4 < 4; ++q4) {
      float4 va = *(const float4*)&wa[c][og * 16 + q4 * 4];
      float4 vc = *(const float4*)&wc[c][og * 16 + q4 * 4];
      aa0[q4*4+0] += va.x * xv0; aa0[q4*4+1] += va.y * xv0;
      aa0[q4*4+2] += va.z * xv0; aa0[q4*4+3] += va.w * xv0;
      ac0[q4*4+0] += vc.x * xv0; ac0[q4*4+1] += vc.y * xv0;
      ac0[q4*4+2] += vc.z * xv0; ac0[q4*4+3] += vc.w * xv0;
      aa1[q4*4+0] += va.x * xv1; aa1[q4*4+1] += va.y * xv1;
      aa1[q4*4+2] += va.z * xv1; aa1[q4*4+3] += va.w * xv1;
      ac1[q4*4+0] += vc.x * xv1; ac1[q4*4+1] += vc.y * xv1;
      ac1[q4*4+2] += vc.z * xv1; ac1[q4*4+3] += vc.w * xv1;
    }
  }
  size_t ga0 = (size_t)(g0 + nl) * ODIM + og * 16;
  size_t ga1 = (size_t)(g0 + 64 + nl) * ODIM + og * 16;
  #pragma unroll
  for (int q4 = 0; q4 < 4; ++q4) {
    *(float4*)&a [ga0 + q4 * 4] = *(float4*)&aa0[q4 * 4];
    *(float4*)&cc[ga0 + q4 * 4] = *(float4*)&ac0[q4 * 4];
    *(float4*)&a [ga1 + q4 * 4] = *(float4*)&aa1[q4 * 4];
    *(float4*)&cc[ga1 + q4 * 4] = *(float4*)&ac1[q4 * 4];
  }
}

// ---------------------------------------------------------------------------
// out[b][o][n] = relu(inv[o] * max_k(a[b][n][o] + cc[b][knn[n][k]][o]) + bias[o])
// ---------------------------------------------------------------------------
__global__ __launch_bounds__(256) void out_kernel(const float* __restrict__ a,
                                                  const float* __restrict__ cc,
                                                  const int* __restrict__ knn,
                                                  const float* __restrict__ gamma,
                                                  const float* __restrict__ beta,
                                                  const float* __restrict__ mean,
                                                  const float* __restrict__ var,
                                                  float* __restrict__ out) {
  __shared__ float tile[64][65];
  const int tid = threadIdx.x, lane = tid & 63, wv = tid >> 6;
  const int b = blockIdx.y;
  const int n0 = blockIdx.x * 64;
  float inv  = gamma[lane] / sqrtf(var[lane] + 1e-5f);
  float bias = beta[lane] - mean[lane] * inv;
  for (int t = 0; t < 16; ++t) {
    int nl = wv * 16 + t;
    size_t base = (size_t)b * NPTS + (n0 + nl);
    float av = a[base * ODIM + lane];
    const int* kr = knn + base * KNN;
    float m = -INFINITY;
    #pragma unroll
    for (int k = 0; k < KNN; ++k) {
      int j = kr[k];
      float cv = cc[((size_t)b * NPTS + j) * ODIM + lane];
      m = fmaxf(m, av + cv);
    }
    float v = m * inv + bias;
    tile[nl][lane] = v > 0.f ? v : 0.f;
  }
  __syncthreads();
  for (int t = 0; t < 16; ++t) {
    int o = wv * 16 + t;
    out[((size_t)b * ODIM + o) * NPTS + n0 + lane] = tile[lane][o];
  }
}

// ---------------------------------------------------------------------------
extern "C" void kernel_launch(void* const* d_in, const int* in_sizes, int n_in,
                              void* d_out, int out_size, void* d_ws, size_t ws_size,
                              hipStream_t stream) {
  const float* x     = (const float*)d_in[0];
  const float* w     = (const float*)d_in[1];
  const float* gamma = (const float*)d_in[2];
  const float* beta  = (const float*)d_in[3];
  const float* mean  = (const float*)d_in[4];
  const float* var   = (const float*)d_in[5];
  float* out = (float*)d_out;

  char* wsb = (char*)d_ws;
  size_t off = 0;
  int*   knn = (int*)(wsb + off);   off += (size_t)BDIM * NPTS * KNN * 4;   // 2.62 MB
  float* sq  = (float*)(wsb + off); off += (size_t)BDIM * NPTS * 4;         // 0.13 MB
  float* a   = (float*)(wsb + off); off += (size_t)BDIM * NPTS * ODIM * 4;  // 8 MB
  float* cc  = (float*)(wsb + off); off += (size_t)BDIM * NPTS * ODIM * 4;  // 8 MB
  float* dist = (float*)(wsb + off);

  int chunk = 128;
  for (int c2 = 8192; c2 >= 128; c2 >>= 1) {
    if (off + (size_t)c2 * NPTS * 4 <= ws_size) { chunk = c2; break; }
  }

  sq_kernel  <<<BDIM * NPTS / 256, 256, 0, stream>>>(x, sq);
  proj_kernel<<<BDIM * NPTS / 128, 256, 0, stream>>>(x, w, a, cc);

  const int total_rows = BDIM * NPTS;
  for (int g0 = 0; g0 < total_rows; g0 += chunk) {
    dist_gemm  <<<dim3(NPTS / 128, chunk / 128), 256, 0, stream>>>(x, sq, dist, g0);
    topk_kernel<<<chunk / 4, 256, 0, stream>>>(dist, knn, g0);
  }

  out_kernel<<<dim3(NPTS / 64, BDIM), 256, 0, stream>>>(a, cc, knn, gamma, beta,
                                                        mean, var, out);
}